// Round 7
// baseline (477.833 us; speedup 1.0000x reference)
//
#include <hip/hip_runtime.h>
#include <hip/hip_bf16.h>
#include <cstdint>

#define BB 8
#define SS 3840
#define RR (BB*SS)                 // 30720 rows per modality
#define NHALF ((size_t)RR * 256)   // elems per half plane

typedef short s16x8 __attribute__((ext_vector_type(8)));
typedef float f32x4 __attribute__((ext_vector_type(4)));

__device__ __forceinline__ ushort f2bf(float f) {
    uint32_t u = __builtin_bit_cast(uint32_t, f);
    u += 0x7FFFu + ((u >> 16) & 1u);
    return (ushort)(u >> 16);
}
__device__ __forceinline__ float bf2f(ushort h) {
    return __builtin_bit_cast(float, (uint32_t)h << 16);
}

#define GLDS16(gp, lp) __builtin_amdgcn_global_load_lds( \
    (const __attribute__((address_space(1))) uint32_t*)(gp), \
    (__attribute__((address_space(3))) uint32_t*)(lp), 16, 0, 0)

// ---------------- all weight prep in one kernel ----------------
__global__ __launch_bounds__(256) void wtrans_all(
    const float* __restrict__ Wv, const float* __restrict__ Wo,
    const float* __restrict__ Wa, const float* __restrict__ Wp,
    const float* __restrict__ W1, const float* __restrict__ W2,
    const float* __restrict__ bo, const float* __restrict__ ba,
    ushort* __restrict__ Wvt, ushort* __restrict__ Woat, ushort* __restrict__ Wpt,
    ushort* __restrict__ W1t, ushort* __restrict__ W2t, float* __restrict__ boa)
{
    int e = blockIdx.x * 256 + threadIdx.x;
    if (e < 65536)       { int k = e >> 8, n = e & 255;  Wvt[n * 256 + k] = f2bf(Wv[e]); }
    else if (e < 98304)  { int i = e - 65536;  int k = i >> 7, n = i & 127;  Woat[n * 256 + k] = f2bf(Wo[i]); }
    else if (e < 131072) { int i = e - 98304;  int k = i >> 7, n = i & 127;  Woat[(n + 128) * 256 + k] = f2bf(Wa[i]); }
    else if (e < 196608) { int i = e - 131072; int k = i >> 8, n = i & 255;  Wpt[n * 256 + k] = f2bf(Wp[i]); }
    else if (e < 458752) { int i = e - 196608; int k = i >> 10, n = i & 1023; W1t[n * 256 + k] = f2bf(W1[i]); }
    else if (e < 720896) { int i = e - 458752; int k = i >> 8, n = i & 255;  W2t[(size_t)n * 1024 + k] = f2bf(W2[i]); }
    else if (e < 721152) { int t = e - 720896; boa[t] = (t < 128) ? bo[t] : ba[t - 128]; }
}

// ---------------- pack both modalities ----------------
__global__ __launch_bounds__(256) void pack2_cat(
    const float* __restrict__ vs, const float* __restrict__ as_,
    const float* __restrict__ vp, const float* __restrict__ ap,
    ushort* __restrict__ sb, ushort* __restrict__ qb)
{
    const int n4 = (int)(NHALF / 4);
    int i = blockIdx.x * 256 + threadIdx.x;
    int j = (i < n4) ? i : i - n4;
    const float4* s4 = (const float4*)((i < n4) ? vs : as_);
    const float4* p4 = (const float4*)((i < n4) ? vp : ap);
    float4 a = s4[j];
    float4 b = p4[j];
    ushort4 u, v;
    u.x = f2bf(a.x); u.y = f2bf(a.y); u.z = f2bf(a.z); u.w = f2bf(a.w);
    v.x = f2bf(a.x + b.x); v.y = f2bf(a.y + b.y); v.z = f2bf(a.z + b.z); v.w = f2bf(a.w + b.w);
    ((ushort4*)sb)[i] = u;
    ((ushort4*)qb)[i] = v;
}

// ---------------- fused value+offaw GEMM, grid (4, 480) y-major ----------------
// blockIdx.x: bit1 = job (0 value, 1 offaw), bit0 = N-half (bn 0/128). blockIdx.y = bm tile.
__global__ __launch_bounds__(256) void gemm_fused(
    const ushort* __restrict__ Av0, const ushort* __restrict__ Av1,
    const ushort* __restrict__ Ao0, const ushort* __restrict__ Ao1,
    const ushort* __restrict__ WvT, const ushort* __restrict__ WoT,
    const float* __restrict__ bv, const float* __restrict__ boa,
    ushort* __restrict__ val_out,
    float* __restrict__ loc0, float* __restrict__ loc1,
    float* __restrict__ aw0, float* __restrict__ aw1,
    const float* __restrict__ ref0, const float* __restrict__ ref1,
    const int* __restrict__ ts0, const int* __restrict__ ts1,
    const unsigned char* __restrict__ mask0, const unsigned char* __restrict__ mask1)
{
    __shared__ ushort As[128 * 64];
    __shared__ ushort Bs[128 * 64];
    const int tid = threadIdx.x;
    const int lane = tid & 63;
    const int wid = tid >> 6;
    const int wr = wid >> 1, wc = wid & 1;
    const int job = blockIdx.x >> 1;
    const int bn = (blockIdx.x & 1) << 7;
    const int bm = blockIdx.y << 7;
    const int half = bm >= RR;
    const int bmL = half ? bm - RR : bm;
    const int l15 = lane & 15;
    const int l4 = lane >> 4;

    const ushort* A = job ? (half ? Ao1 : Ao0) : (half ? Av1 : Av0);
    const ushort* Wt = job ? WoT : WvT;
    A += (size_t)bmL * 256;

    f32x4 acc[4][4] = {};

    for (int k0 = 0; k0 < 256; k0 += 64) {
        #pragma unroll
        for (int r = 0; r < 4; ++r) {
            int base = r * 256 + (wid << 6);
            int idx = base + lane;
            int row = idx >> 3, sl = idx & 7;
            int ch = sl ^ (row & 7);
            GLDS16(&A[(size_t)row * 256 + k0 + ch * 8], &As[base << 3]);
        }
        #pragma unroll
        for (int r = 0; r < 4; ++r) {
            int base = r * 256 + (wid << 6);
            int idx = base + lane;
            int col = idx >> 3, sl = idx & 7;
            int ch = sl ^ (col & 7);
            GLDS16(&Wt[(size_t)(bn + col) * 256 + k0 + ch * 8], &Bs[base << 3]);
        }
        __syncthreads();
        #pragma unroll
        for (int ks = 0; ks < 2; ++ks) {
            s16x8 af[4], bf[4];
            const int k16 = ks * 4 + l4;
            #pragma unroll
            for (int m = 0; m < 4; ++m) {
                int row = (wr << 6) + (m << 4) + l15;
                af[m] = *(const s16x8*)&As[(row << 6) + ((k16 ^ (row & 7)) << 3)];
            }
            #pragma unroll
            for (int n = 0; n < 4; ++n) {
                int col = (wc << 6) + (n << 4) + l15;
                bf[n] = *(const s16x8*)&Bs[(col << 6) + ((k16 ^ (col & 7)) << 3)];
            }
            #pragma unroll
            for (int m = 0; m < 4; ++m)
                #pragma unroll
                for (int n = 0; n < 4; ++n)
                    acc[m][n] = __builtin_amdgcn_mfma_f32_16x16x32_bf16(af[m], bf[n], acc[m][n], 0, 0, 0);
        }
        __syncthreads();
    }

    const int l4r = l4 << 2;
    if (job == 0) {
        const unsigned char* mk = half ? mask1 : mask0;
        ushort* vo = val_out + (size_t)half * NHALF;
        #pragma unroll
        for (int m = 0; m < 4; ++m) {
            #pragma unroll
            for (int r = 0; r < 4; ++r) {
                const int rowL = bmL + (wr << 6) + (m << 4) + l4r + r;
                const int b = rowL / SS;
                const int s = rowL - b * SS;
                const float mz = mk[rowL] ? 0.f : 1.f;
                const size_t rb = ((size_t)(b * 8) * SS + s) * 32;
                #pragma unroll
                for (int n = 0; n < 4; ++n) {
                    const int col = bn + (wc << 6) + (n << 4) + l15;
                    const int h = col >> 5, d = col & 31;
                    vo[rb + (size_t)h * (SS * 32) + d] = f2bf((acc[m][n][r] + bv[col]) * mz);
                }
            }
        }
    } else if (bn == 0) {
        const float* rf = half ? ref1 : ref0;
        const int* tsp = half ? ts1 : ts0;
        const int l = l15 >> 2;
        const float T = (float)tsp[l];
        float* lo = half ? loc1 : loc0;
        #pragma unroll
        for (int m = 0; m < 4; ++m) {
            #pragma unroll
            for (int r = 0; r < 4; ++r) {
                const int rowL = bmL + (wr << 6) + (m << 4) + l4r + r;
                const float refv = rf[(size_t)rowL * 4 + l];
                #pragma unroll
                for (int n = 0; n < 4; ++n) {
                    const int cc = (wc << 6) + (n << 4) + l15;
                    lo[(size_t)rowL * 128 + cc] = refv + (acc[m][n][r] + boa[cc]) / T;
                }
            }
        }
    } else {
        float* ao = half ? aw1 : aw0;
        #pragma unroll
        for (int m = 0; m < 4; ++m) {
            #pragma unroll
            for (int r = 0; r < 4; ++r) {
                const int rowL = bmL + (wr << 6) + (m << 4) + l4r + r;
                #pragma unroll
                for (int n = 0; n < 4; ++n) {
                    const int cc = (wc << 6) + (n << 4) + l15;
                    float c = acc[m][n][r] + boa[128 + cc];
                    float mx = c;
                    #pragma unroll
                    for (int o = 1; o < 16; o <<= 1) mx = fmaxf(mx, __shfl_xor(mx, o));
                    float e = __expf(c - mx);
                    float sm = e;
                    #pragma unroll
                    for (int o = 1; o < 16; o <<= 1) sm += __shfl_xor(sm, o);
                    ao[(size_t)rowL * 128 + cc] = e / sm;
                }
            }
        }
    }
}

// ---------------- 8-wave 128x256 GEMM with fused epilogues ----------------
// EPI 0: + bias -> bf16 (proj P34)
// EPI 1: + bias + f32 residual -> LN -> bf16 (proj+LN1)
// EPI 2: + bias -> relu -> bf16 (FFN W1, N=1024; grid (4,480) y-major)
// EPI 3: + bias + bf16 residual -> LN -> f32 by half (FFN W2+LN2)
template<int EPI>
__global__ __launch_bounds__(512) void gemm256(
    const ushort* __restrict__ A, const ushort* __restrict__ Wt,
    const float* __restrict__ bias, int N, int K,
    ushort* __restrict__ outb,
    const float* __restrict__ res0, const float* __restrict__ res1,
    const ushort* __restrict__ resb,
    const float* __restrict__ g, const float* __restrict__ be,
    float* __restrict__ of0, float* __restrict__ of1)
{
    __shared__ ushort As[128 * 64];
    __shared__ ushort Bs[256 * 64];
    __shared__ float redS[128][4];
    __shared__ float redQ[128][4];
    __shared__ float redM[128];
    __shared__ float redR[128];

    const int tid = threadIdx.x;
    const int lane = tid & 63;
    const int wid = tid >> 6;          // 0..7
    const int wr = wid >> 2, wc = wid & 3;
    const int bm = (EPI == 2 ? blockIdx.y : blockIdx.x) << 7;
    const int bn = (EPI == 2 ? blockIdx.x : blockIdx.y) << 8;
    const int l15 = lane & 15;
    const int l4 = lane >> 4;

    f32x4 acc[4][4] = {};

    for (int k0 = 0; k0 < K; k0 += 64) {
        #pragma unroll
        for (int r = 0; r < 2; ++r) {
            int base = r * 512 + (wid << 6);
            int idx = base + lane;
            int row = idx >> 3, sl = idx & 7;
            int ch = sl ^ (row & 7);
            GLDS16(&A[(size_t)(bm + row) * K + k0 + ch * 8], &As[base << 3]);
        }
        #pragma unroll
        for (int r = 0; r < 4; ++r) {
            int base = r * 512 + (wid << 6);
            int idx = base + lane;
            int col = idx >> 3, sl = idx & 7;
            int ch = sl ^ (col & 7);
            GLDS16(&Wt[(size_t)(bn + col) * K + k0 + ch * 8], &Bs[base << 3]);
        }
        __syncthreads();
        #pragma unroll
        for (int ks = 0; ks < 2; ++ks) {
            s16x8 af[4], bf[4];
            const int k16 = ks * 4 + l4;
            #pragma unroll
            for (int m = 0; m < 4; ++m) {
                int row = (wr << 6) + (m << 4) + l15;
                af[m] = *(const s16x8*)&As[(row << 6) + ((k16 ^ (row & 7)) << 3)];
            }
            #pragma unroll
            for (int n = 0; n < 4; ++n) {
                int col = (wc << 6) + (n << 4) + l15;
                bf[n] = *(const s16x8*)&Bs[(col << 6) + ((k16 ^ (col & 7)) << 3)];
            }
            #pragma unroll
            for (int m = 0; m < 4; ++m)
                #pragma unroll
                for (int n = 0; n < 4; ++n)
                    acc[m][n] = __builtin_amdgcn_mfma_f32_16x16x32_bf16(af[m], bf[n], acc[m][n], 0, 0, 0);
        }
        __syncthreads();
    }

    const int half = bm >= RR;
    const int bmL = half ? bm - RR : bm;

    if (EPI == 0 || EPI == 2) {
        #pragma unroll
        for (int m = 0; m < 4; ++m) {
            #pragma unroll
            for (int r = 0; r < 4; ++r) {
                const int row = bm + (wr << 6) + (m << 4) + (l4 << 2) + r;
                #pragma unroll
                for (int n = 0; n < 4; ++n) {
                    const int col = bn + (wc << 6) + (n << 4) + l15;
                    float c = acc[m][n][r] + bias[col];
                    if (EPI == 2) c = fmaxf(c, 0.f);
                    outb[(size_t)row * N + col] = f2bf(c);
                }
            }
        }
        return;
    }

    #pragma unroll
    for (int m = 0; m < 4; ++m) {
        #pragma unroll
        for (int r = 0; r < 4; ++r) {
            const int rowb = (wr << 6) + (m << 4) + (l4 << 2) + r;
            float s1 = 0.f, s2 = 0.f;
            #pragma unroll
            for (int n = 0; n < 4; ++n) {
                const int col = (wc << 6) + (n << 4) + l15;
                float x = acc[m][n][r] + bias[col];
                if (EPI == 1) {
                    const float* res = half ? res1 : res0;
                    x += res[(size_t)(bmL + rowb) * 256 + col];
                } else {
                    x += bf2f(resb[(size_t)(bm + rowb) * 256 + col]);
                }
                acc[m][n][r] = x;
                s1 += x;
                s2 += x * x;
            }
            #pragma unroll
            for (int o = 1; o < 16; o <<= 1) {
                s1 += __shfl_xor(s1, o);
                s2 += __shfl_xor(s2, o);
            }
            if (l15 == 0) { redS[rowb][wc] = s1; redQ[rowb][wc] = s2; }
        }
    }
    __syncthreads();
    if (tid < 128) {
        const float S1 = redS[tid][0] + redS[tid][1] + redS[tid][2] + redS[tid][3];
        const float S2 = redQ[tid][0] + redQ[tid][1] + redQ[tid][2] + redQ[tid][3];
        const float mu = S1 * (1.f / 256.f);
        float var = S2 * (1.f / 256.f) - mu * mu;
        var = fmaxf(var, 0.f);
        redM[tid] = mu;
        redR[tid] = rsqrtf(var + 1e-5f);
    }
    __syncthreads();
    #pragma unroll
    for (int m = 0; m < 4; ++m) {
        #pragma unroll
        for (int r = 0; r < 4; ++r) {
            const int rowb = (wr << 6) + (m << 4) + (l4 << 2) + r;
            const float mu = redM[rowb];
            const float rs = redR[rowb];
            #pragma unroll
            for (int n = 0; n < 4; ++n) {
                const int col = (wc << 6) + (n << 4) + l15;
                const float y = (acc[m][n][r] - mu) * rs * g[col] + be[col];
                if (EPI == 1) {
                    outb[(size_t)(bm + rowb) * 256 + col] = f2bf(y);
                } else {
                    float* of = half ? of1 : of0;
                    of[(size_t)(bmL + rowb) * 256 + col] = y;
                }
            }
        }
    }
}

// ---------------- deformable sampling ----------------
// XCD batch-affinity: xcd = wgid&7 processes batch b==xcd (video then audio)
// so each XCD's value working set = 2 x 1.97MB ~ one L2. Desc LDS padded
// (stride 17) so the 8 h-groups hit distinct banks.
struct Desc { float wa, wb; int oa, ob; };

__global__ __launch_bounds__(256) void msda_sample(
    const ushort* __restrict__ value,
    const float* __restrict__ l0, const float* __restrict__ l1,
    const float* __restrict__ a0, const float* __restrict__ a1,
    const int* __restrict__ ts0, const int* __restrict__ lsi0,
    const int* __restrict__ ts1, const int* __restrict__ lsi1,
    ushort* __restrict__ out)
{
    __shared__ Desc ds[544];   // [4 rows][8 h][17 pad] -> (rl*8+h)*17 + lp
    const int tid = threadIdx.x;
    const int wg = blockIdx.x;
    const int xcd = wg & 7;
    const int idx = wg >> 3;               // 0..1919
    const int half = idx >= 960;
    const int rowL0 = xcd * SS + (half ? idx - 960 : idx) * 4;
    const int row0 = rowL0 + (half ? RR : 0);

    const float* loc = half ? l1 : l0;
    const float* aw  = half ? a1 : a0;
    const int* ts  = half ? ts1 : ts0;
    const int* lsi = half ? lsi1 : lsi0;
    const ushort* val = value + (size_t)half * NHALF;

    #pragma unroll
    for (int d = tid; d < 512; d += 256) {
        const int rl = d >> 7;
        const int rem = d & 127;           // h*16 + l*4 + p
        const int l = (rem >> 2) & 3;
        const int h = rem >> 4;
        const int lp = rem & 15;
        const int rowL = rowL0 + rl;
        const float lc = loc[(size_t)rowL * 128 + rem];
        const float w  = aw[(size_t)rowL * 128 + rem];
        const int T = ts[l];
        const int s0 = lsi[l];
        const int b = rowL / SS;
        const float pos = lc * (float)T - 0.5f;
        const float x0 = floorf(pos);
        const float w1 = pos - x0;
        const int i0 = (int)x0;
        const int i1 = i0 + 1;
        const int base = (b * 8 + h) * SS + s0;
        Desc e;
        e.wa = (i0 >= 0 && i0 < T) ? w * (1.f - w1) : 0.f;
        e.wb = (i1 >= 0 && i1 < T) ? w * w1 : 0.f;
        const int ia = min(max(i0, 0), T - 1);
        const int ib = min(max(i1, 0), T - 1);
        e.oa = (base + ia) << 5;
        e.ob = (base + ib) << 5;
        ds[(rl * 8 + h) * 17 + lp] = e;
    }
    __syncthreads();

    const int rl = tid >> 6;
    const int h  = (tid >> 3) & 7;
    const int cq = tid & 7;
    const ushort* vb = val + cq * 4;
    const Desc* dd = &ds[(rl * 8 + h) * 17];

    f32x4 acc0 = {}, acc1 = {};
    #pragma unroll
    for (int lp = 0; lp < 16; lp += 2) {
        const Desc e0 = dd[lp];
        const Desc e1 = dd[lp + 1];
        const uint2 A0 = *(const uint2*)(vb + e0.oa);
        const uint2 B0 = *(const uint2*)(vb + e0.ob);
        const uint2 A1 = *(const uint2*)(vb + e1.oa);
        const uint2 B1 = *(const uint2*)(vb + e1.ob);
        #pragma unroll
        for (int c = 0; c < 2; ++c) {
            const uint32_t ua = (c ? A0.y : A0.x), ub = (c ? B0.y : B0.x);
            const uint32_t va = (c ? A1.y : A1.x), vw = (c ? B1.y : B1.x);
            acc0[2*c+0] = fmaf(e0.wa, __builtin_bit_cast(float, ua << 16), acc0[2*c+0]);
            acc0[2*c+1] = fmaf(e0.wa, __builtin_bit_cast(float, ua & 0xFFFF0000u), acc0[2*c+1]);
            acc0[2*c+0] = fmaf(e0.wb, __builtin_bit_cast(float, ub << 16), acc0[2*c+0]);
            acc0[2*c+1] = fmaf(e0.wb, __builtin_bit_cast(float, ub & 0xFFFF0000u), acc0[2*c+1]);
            acc1[2*c+0] = fmaf(e1.wa, __builtin_bit_cast(float, va << 16), acc1[2*c+0]);
            acc1[2*c+1] = fmaf(e1.wa, __builtin_bit_cast(float, va & 0xFFFF0000u), acc1[2*c+1]);
            acc1[2*c+0] = fmaf(e1.wb, __builtin_bit_cast(float, vw << 16), acc1[2*c+0]);
            acc1[2*c+1] = fmaf(e1.wb, __builtin_bit_cast(float, vw & 0xFFFF0000u), acc1[2*c+1]);
        }
    }
    ushort4 o;
    o.x = f2bf(acc0[0] + acc1[0]);
    o.y = f2bf(acc0[1] + acc1[1]);
    o.z = f2bf(acc0[2] + acc1[2]);
    o.w = f2bf(acc0[3] + acc1[3]);
    *(ushort4*)&out[(size_t)(row0 + rl) * 256 + h * 32 + cq * 4] = o;
}

extern "C" void kernel_launch(void* const* d_in, const int* in_sizes, int n_in,
                              void* d_out, int out_size, void* d_ws, size_t ws_size,
                              hipStream_t stream) {
    const float* video_src = (const float*)d_in[0];
    const float* audio_src = (const float*)d_in[1];
    const float* video_pos = (const float*)d_in[2];
    const float* audio_pos = (const float*)d_in[3];
    const float* video_ref = (const float*)d_in[4];
    const float* audio_ref = (const float*)d_in[5];
    const int*   video_ts  = (const int*)d_in[6];
    const int*   video_lsi = (const int*)d_in[7];
    const unsigned char* video_mask = (const unsigned char*)d_in[8];
    const int*   audio_ts  = (const int*)d_in[9];
    const int*   audio_lsi = (const int*)d_in[10];
    const unsigned char* audio_mask = (const unsigned char*)d_in[11];
    const float* Wv = (const float*)d_in[12];
    const float* bv = (const float*)d_in[13];
    const float* Wo = (const float*)d_in[14];
    const float* bo = (const float*)d_in[15];
    const float* Wa = (const float*)d_in[16];
    const float* ba = (const float*)d_in[17];
    const float* Wp = (const float*)d_in[18];
    const float* bp = (const float*)d_in[19];
    const float* ln1_g = (const float*)d_in[20];
    const float* ln1_b = (const float*)d_in[21];
    const float* W1 = (const float*)d_in[22];
    const float* b1 = (const float*)d_in[23];
    const float* W2 = (const float*)d_in[24];
    const float* b2 = (const float*)d_in[25];
    const float* ln2_g = (const float*)d_in[26];
    const float* ln2_b = (const float*)d_in[27];

    float* out = (float*)d_out;
    const size_t n = NHALF;
    float* out_aav  = out;
    float* out_vaa  = out + n;
    float* out_vloc = out + 2 * n;
    float* out_vaw  = out + 2 * n + n / 2;
    float* out_aloc = out + 3 * n;
    float* out_aaw  = out + 3 * n + n / 2;

    const size_t UB = NHALF * 2;   // one bf16 plane, bytes
    char* base = (char*)d_ws;
    ushort* src_cat   = (ushort*)(base + 0 * UB);   // P12
    ushort* q_cat     = (ushort*)(base + 2 * UB);   // P12
    float*  loc_tmp   = (float*) (base + 4 * UB);   // P12
    float*  aw_tmp    = (float*) (base + 6 * UB);   // P12
    ushort* hid       = (ushort*)(base + 0 * UB);   // P34 FFN hidden [0,8U)
    ushort* value_cat = (ushort*)(base + 8 * UB);
    ushort* samp_cat  = (ushort*)(base + 10 * UB);
    ushort* vb_cat    = (ushort*)(base + 12 * UB);
    ushort* proj_b34  = (ushort*)(base + 12 * UB);  // overwrites vb_cat after P34 gemm_fused
    ushort* Wvt  = (ushort*)(base + 14 * UB);
    ushort* Woat = Wvt + 65536;
    ushort* Wpt  = Woat + 65536;
    ushort* W1t  = Wpt + 65536;
    ushort* W2t  = W1t + 262144;
    float*  boa  = (float*)(W2t + 262144);

    wtrans_all<<<2817, 256, 0, stream>>>(Wv, Wo, Wa, Wp, W1, W2, bo, ba,
                                         Wvt, Woat, Wpt, W1t, W2t, boa);
    pack2_cat<<<15360, 256, 0, stream>>>(video_src, audio_src, video_pos, audio_pos,
                                         src_cat, q_cat);

    // ---- Phase 1+2: self-attention ----
    gemm_fused<<<dim3(4, 480), 256, 0, stream>>>(
        src_cat, src_cat + NHALF, q_cat, q_cat + NHALF,
        Wvt, Woat, bv, boa, value_cat,
        loc_tmp, loc_tmp + (size_t)RR * 128, aw_tmp, aw_tmp + (size_t)RR * 128,
        video_ref, audio_ref, video_ts, audio_ts, video_mask, audio_mask);
    msda_sample<<<15360, 256, 0, stream>>>(
        value_cat, loc_tmp, loc_tmp + (size_t)RR * 128, aw_tmp, aw_tmp + (size_t)RR * 128,
        video_ts, video_lsi, audio_ts, audio_lsi, samp_cat);
    gemm256<1><<<dim3(480, 1), 512, 0, stream>>>(
        samp_cat, Wpt, bp, 256, 256, vb_cat,
        video_src, audio_src, nullptr, ln1_g, ln1_b, nullptr, nullptr);

    // ---- Phase 3+4: cross-attention + FFN ----
    gemm_fused<<<dim3(4, 480), 256, 0, stream>>>(
        vb_cat, vb_cat + NHALF,
        vb_cat + NHALF, vb_cat,
        Wvt, Woat, bv, boa, value_cat,
        out_aloc, out_vloc, out_aaw, out_vaw,
        audio_ref, video_ref, video_ts, audio_ts, video_mask, audio_mask);
    msda_sample<<<15360, 256, 0, stream>>>(
        value_cat, out_aloc, out_vloc, out_aaw, out_vaw,
        video_ts, video_lsi, audio_ts, audio_lsi, samp_cat);
    gemm256<0><<<dim3(480, 1), 512, 0, stream>>>(
        samp_cat, Wpt, bp, 256, 256, proj_b34,
        nullptr, nullptr, nullptr, nullptr, nullptr, nullptr, nullptr);
    gemm256<2><<<dim3(4, 480), 512, 0, stream>>>(
        proj_b34, W1t, b1, 1024, 256, hid,
        nullptr, nullptr, nullptr, nullptr, nullptr, nullptr, nullptr);
    gemm256<3><<<dim3(480, 1), 512, 0, stream>>>(
        hid, W2t, b2, 256, 1024, nullptr,
        nullptr, nullptr, proj_b34, ln2_g, ln2_b, out_vaa, out_aav);
}

// Round 8
// 436.733 us; speedup vs baseline: 1.0941x; 1.0941x over previous
//
#include <hip/hip_runtime.h>
#include <hip/hip_bf16.h>
#include <cstdint>

#define BB 8
#define SS 3840
#define RR (BB*SS)                 // 30720 rows per modality
#define NHALF ((size_t)RR * 256)   // elems per half plane

typedef short s16x8 __attribute__((ext_vector_type(8)));
typedef float f32x4 __attribute__((ext_vector_type(4)));

__device__ __forceinline__ ushort f2bf(float f) {
    uint32_t u = __builtin_bit_cast(uint32_t, f);
    u += 0x7FFFu + ((u >> 16) & 1u);
    return (ushort)(u >> 16);
}
__device__ __forceinline__ float bf2f(ushort h) {
    return __builtin_bit_cast(float, (uint32_t)h << 16);
}

#define GLDS16(gp, lp) __builtin_amdgcn_global_load_lds( \
    (const __attribute__((address_space(1))) uint32_t*)(gp), \
    (__attribute__((address_space(3))) uint32_t*)(lp), 16, 0, 0)

// ---------------- all weight prep in one kernel ----------------
__global__ __launch_bounds__(256) void wtrans_all(
    const float* __restrict__ Wv, const float* __restrict__ Wo,
    const float* __restrict__ Wa, const float* __restrict__ Wp,
    const float* __restrict__ W1, const float* __restrict__ W2,
    const float* __restrict__ bo, const float* __restrict__ ba,
    ushort* __restrict__ Wvt, ushort* __restrict__ Woat, ushort* __restrict__ Wpt,
    ushort* __restrict__ W1t, ushort* __restrict__ W2t, float* __restrict__ boa)
{
    int e = blockIdx.x * 256 + threadIdx.x;
    if (e < 65536)       { int k = e >> 8, n = e & 255;  Wvt[n * 256 + k] = f2bf(Wv[e]); }
    else if (e < 98304)  { int i = e - 65536;  int k = i >> 7, n = i & 127;  Woat[n * 256 + k] = f2bf(Wo[i]); }
    else if (e < 131072) { int i = e - 98304;  int k = i >> 7, n = i & 127;  Woat[(n + 128) * 256 + k] = f2bf(Wa[i]); }
    else if (e < 196608) { int i = e - 131072; int k = i >> 8, n = i & 255;  Wpt[n * 256 + k] = f2bf(Wp[i]); }
    else if (e < 458752) { int i = e - 196608; int k = i >> 10, n = i & 1023; W1t[n * 256 + k] = f2bf(W1[i]); }
    else if (e < 720896) { int i = e - 458752; int k = i >> 8, n = i & 255;  W2t[(size_t)n * 1024 + k] = f2bf(W2[i]); }
    else if (e < 721152) { int t = e - 720896; boa[t] = (t < 128) ? bo[t] : ba[t - 128]; }
}

// ---------------- pack both modalities ----------------
__global__ __launch_bounds__(256) void pack2_cat(
    const float* __restrict__ vs, const float* __restrict__ as_,
    const float* __restrict__ vp, const float* __restrict__ ap,
    ushort* __restrict__ sb, ushort* __restrict__ qb)
{
    const int n4 = (int)(NHALF / 4);
    int i = blockIdx.x * 256 + threadIdx.x;
    int j = (i < n4) ? i : i - n4;
    const float4* s4 = (const float4*)((i < n4) ? vs : as_);
    const float4* p4 = (const float4*)((i < n4) ? vp : ap);
    float4 a = s4[j];
    float4 b = p4[j];
    ushort4 u, v;
    u.x = f2bf(a.x); u.y = f2bf(a.y); u.z = f2bf(a.z); u.w = f2bf(a.w);
    v.x = f2bf(a.x + b.x); v.y = f2bf(a.y + b.y); v.z = f2bf(a.z + b.z); v.w = f2bf(a.w + b.w);
    ((ushort4*)sb)[i] = u;
    ((ushort4*)qb)[i] = v;
}

// ---------------- fused value+offaw GEMM, grid (480, 4) x-major (phase-separated jobs) ----------------
// blockIdx.y: bit1 = job (0 value, 1 offaw), bit0 = N-half (bn 0/128). blockIdx.x = bm tile.
__global__ __launch_bounds__(256) void gemm_fused(
    const ushort* __restrict__ Av0, const ushort* __restrict__ Av1,
    const ushort* __restrict__ Ao0, const ushort* __restrict__ Ao1,
    const ushort* __restrict__ WvT, const ushort* __restrict__ WoT,
    const float* __restrict__ bv, const float* __restrict__ boa,
    ushort* __restrict__ val_out,
    float* __restrict__ loc0, float* __restrict__ loc1,
    float* __restrict__ aw0, float* __restrict__ aw1,
    const float* __restrict__ ref0, const float* __restrict__ ref1,
    const int* __restrict__ ts0, const int* __restrict__ ts1,
    const unsigned char* __restrict__ mask0, const unsigned char* __restrict__ mask1)
{
    __shared__ ushort As[128 * 64];
    __shared__ ushort Bs[128 * 64];
    const int tid = threadIdx.x;
    const int lane = tid & 63;
    const int wid = tid >> 6;
    const int wr = wid >> 1, wc = wid & 1;
    const int job = blockIdx.y >> 1;
    const int bn = (blockIdx.y & 1) << 7;
    const int bm = blockIdx.x << 7;
    const int half = bm >= RR;
    const int bmL = half ? bm - RR : bm;
    const int l15 = lane & 15;
    const int l4 = lane >> 4;

    const ushort* A = job ? (half ? Ao1 : Ao0) : (half ? Av1 : Av0);
    const ushort* Wt = job ? WoT : WvT;
    A += (size_t)bmL * 256;

    f32x4 acc[4][4] = {};

    for (int k0 = 0; k0 < 256; k0 += 64) {
        #pragma unroll
        for (int r = 0; r < 4; ++r) {
            int base = r * 256 + (wid << 6);
            int idx = base + lane;
            int row = idx >> 3, sl = idx & 7;
            int ch = sl ^ (row & 7);
            GLDS16(&A[(size_t)row * 256 + k0 + ch * 8], &As[base << 3]);
        }
        #pragma unroll
        for (int r = 0; r < 4; ++r) {
            int base = r * 256 + (wid << 6);
            int idx = base + lane;
            int col = idx >> 3, sl = idx & 7;
            int ch = sl ^ (col & 7);
            GLDS16(&Wt[(size_t)(bn + col) * 256 + k0 + ch * 8], &Bs[base << 3]);
        }
        __syncthreads();
        #pragma unroll
        for (int ks = 0; ks < 2; ++ks) {
            s16x8 af[4], bf[4];
            const int k16 = ks * 4 + l4;
            #pragma unroll
            for (int m = 0; m < 4; ++m) {
                int row = (wr << 6) + (m << 4) + l15;
                af[m] = *(const s16x8*)&As[(row << 6) + ((k16 ^ (row & 7)) << 3)];
            }
            #pragma unroll
            for (int n = 0; n < 4; ++n) {
                int col = (wc << 6) + (n << 4) + l15;
                bf[n] = *(const s16x8*)&Bs[(col << 6) + ((k16 ^ (col & 7)) << 3)];
            }
            #pragma unroll
            for (int m = 0; m < 4; ++m)
                #pragma unroll
                for (int n = 0; n < 4; ++n)
                    acc[m][n] = __builtin_amdgcn_mfma_f32_16x16x32_bf16(af[m], bf[n], acc[m][n], 0, 0, 0);
        }
        __syncthreads();
    }

    const int l4r = l4 << 2;
    if (job == 0) {
        const unsigned char* mk = half ? mask1 : mask0;
        ushort* vo = val_out + (size_t)half * NHALF;
        #pragma unroll
        for (int m = 0; m < 4; ++m) {
            #pragma unroll
            for (int r = 0; r < 4; ++r) {
                const int rowL = bmL + (wr << 6) + (m << 4) + l4r + r;
                const int b = rowL / SS;
                const int s = rowL - b * SS;
                const float mz = mk[rowL] ? 0.f : 1.f;
                const size_t rb = ((size_t)(b * 8) * SS + s) * 32;
                #pragma unroll
                for (int n = 0; n < 4; ++n) {
                    const int col = bn + (wc << 6) + (n << 4) + l15;
                    const int h = col >> 5, d = col & 31;
                    vo[rb + (size_t)h * (SS * 32) + d] = f2bf((acc[m][n][r] + bv[col]) * mz);
                }
            }
        }
    } else if (bn == 0) {
        const float* rf = half ? ref1 : ref0;
        const int* tsp = half ? ts1 : ts0;
        const int l = l15 >> 2;
        const float T = (float)tsp[l];
        float* lo = half ? loc1 : loc0;
        #pragma unroll
        for (int m = 0; m < 4; ++m) {
            #pragma unroll
            for (int r = 0; r < 4; ++r) {
                const int rowL = bmL + (wr << 6) + (m << 4) + l4r + r;
                const float refv = rf[(size_t)rowL * 4 + l];
                #pragma unroll
                for (int n = 0; n < 4; ++n) {
                    const int cc = (wc << 6) + (n << 4) + l15;
                    lo[(size_t)rowL * 128 + cc] = refv + (acc[m][n][r] + boa[cc]) / T;
                }
            }
        }
    } else {
        float* ao = half ? aw1 : aw0;
        #pragma unroll
        for (int m = 0; m < 4; ++m) {
            #pragma unroll
            for (int r = 0; r < 4; ++r) {
                const int rowL = bmL + (wr << 6) + (m << 4) + l4r + r;
                #pragma unroll
                for (int n = 0; n < 4; ++n) {
                    const int cc = (wc << 6) + (n << 4) + l15;
                    float c = acc[m][n][r] + boa[128 + cc];
                    float mx = c;
                    #pragma unroll
                    for (int o = 1; o < 16; o <<= 1) mx = fmaxf(mx, __shfl_xor(mx, o));
                    float e = __expf(c - mx);
                    float sm = e;
                    #pragma unroll
                    for (int o = 1; o < 16; o <<= 1) sm += __shfl_xor(sm, o);
                    ao[(size_t)rowL * 128 + cc] = e / sm;
                }
            }
        }
    }
}

// ---------------- 8-wave 128x256 GEMM with fused epilogues ----------------
// EPI 0: + bias -> bf16 (proj P34)
// EPI 1: + bias + f32 residual -> LN -> bf16 (proj+LN1)
// EPI 2: + bias -> relu -> bf16 (FFN W1, N=1024; grid (480,4) x-major)
// EPI 3: + bias + bf16 residual -> LN -> f32 by half (FFN W2+LN2)
template<int EPI>
__global__ __launch_bounds__(512) void gemm256(
    const ushort* __restrict__ A, const ushort* __restrict__ Wt,
    const float* __restrict__ bias, int N, int K,
    ushort* __restrict__ outb,
    const float* __restrict__ res0, const float* __restrict__ res1,
    const ushort* __restrict__ resb,
    const float* __restrict__ g, const float* __restrict__ be,
    float* __restrict__ of0, float* __restrict__ of1)
{
    __shared__ ushort As[128 * 64];
    __shared__ ushort Bs[256 * 64];
    __shared__ float redS[128][4];
    __shared__ float redQ[128][4];
    __shared__ float redM[128];
    __shared__ float redR[128];

    const int tid = threadIdx.x;
    const int lane = tid & 63;
    const int wid = tid >> 6;          // 0..7
    const int wr = wid >> 2, wc = wid & 3;
    const int bm = blockIdx.x << 7;
    const int bn = blockIdx.y << 8;
    const int l15 = lane & 15;
    const int l4 = lane >> 4;

    f32x4 acc[4][4] = {};

    for (int k0 = 0; k0 < K; k0 += 64) {
        #pragma unroll
        for (int r = 0; r < 2; ++r) {
            int base = r * 512 + (wid << 6);
            int idx = base + lane;
            int row = idx >> 3, sl = idx & 7;
            int ch = sl ^ (row & 7);
            GLDS16(&A[(size_t)(bm + row) * K + k0 + ch * 8], &As[base << 3]);
        }
        #pragma unroll
        for (int r = 0; r < 4; ++r) {
            int base = r * 512 + (wid << 6);
            int idx = base + lane;
            int col = idx >> 3, sl = idx & 7;
            int ch = sl ^ (col & 7);
            GLDS16(&Wt[(size_t)(bn + col) * K + k0 + ch * 8], &Bs[base << 3]);
        }
        __syncthreads();
        #pragma unroll
        for (int ks = 0; ks < 2; ++ks) {
            s16x8 af[4], bf[4];
            const int k16 = ks * 4 + l4;
            #pragma unroll
            for (int m = 0; m < 4; ++m) {
                int row = (wr << 6) + (m << 4) + l15;
                af[m] = *(const s16x8*)&As[(row << 6) + ((k16 ^ (row & 7)) << 3)];
            }
            #pragma unroll
            for (int n = 0; n < 4; ++n) {
                int col = (wc << 6) + (n << 4) + l15;
                bf[n] = *(const s16x8*)&Bs[(col << 6) + ((k16 ^ (col & 7)) << 3)];
            }
            #pragma unroll
            for (int m = 0; m < 4; ++m)
                #pragma unroll
                for (int n = 0; n < 4; ++n)
                    acc[m][n] = __builtin_amdgcn_mfma_f32_16x16x32_bf16(af[m], bf[n], acc[m][n], 0, 0, 0);
        }
        __syncthreads();
    }

    const int half = bm >= RR;
    const int bmL = half ? bm - RR : bm;

    if (EPI == 0 || EPI == 2) {
        #pragma unroll
        for (int m = 0; m < 4; ++m) {
            #pragma unroll
            for (int r = 0; r < 4; ++r) {
                const int row = bm + (wr << 6) + (m << 4) + (l4 << 2) + r;
                #pragma unroll
                for (int n = 0; n < 4; ++n) {
                    const int col = bn + (wc << 6) + (n << 4) + l15;
                    float c = acc[m][n][r] + bias[col];
                    if (EPI == 2) c = fmaxf(c, 0.f);
                    outb[(size_t)row * N + col] = f2bf(c);
                }
            }
        }
        return;
    }

    #pragma unroll
    for (int m = 0; m < 4; ++m) {
        #pragma unroll
        for (int r = 0; r < 4; ++r) {
            const int rowb = (wr << 6) + (m << 4) + (l4 << 2) + r;
            float s1 = 0.f, s2 = 0.f;
            #pragma unroll
            for (int n = 0; n < 4; ++n) {
                const int col = (wc << 6) + (n << 4) + l15;
                float x = acc[m][n][r] + bias[col];
                if (EPI == 1) {
                    const float* res = half ? res1 : res0;
                    x += res[(size_t)(bmL + rowb) * 256 + col];
                } else {
                    x += bf2f(resb[(size_t)(bm + rowb) * 256 + col]);
                }
                acc[m][n][r] = x;
                s1 += x;
                s2 += x * x;
            }
            #pragma unroll
            for (int o = 1; o < 16; o <<= 1) {
                s1 += __shfl_xor(s1, o);
                s2 += __shfl_xor(s2, o);
            }
            if (l15 == 0) { redS[rowb][wc] = s1; redQ[rowb][wc] = s2; }
        }
    }
    __syncthreads();
    if (tid < 128) {
        const float S1 = redS[tid][0] + redS[tid][1] + redS[tid][2] + redS[tid][3];
        const float S2 = redQ[tid][0] + redQ[tid][1] + redQ[tid][2] + redQ[tid][3];
        const float mu = S1 * (1.f / 256.f);
        float var = S2 * (1.f / 256.f) - mu * mu;
        var = fmaxf(var, 0.f);
        redM[tid] = mu;
        redR[tid] = rsqrtf(var + 1e-5f);
    }
    __syncthreads();
    #pragma unroll
    for (int m = 0; m < 4; ++m) {
        #pragma unroll
        for (int r = 0; r < 4; ++r) {
            const int rowb = (wr << 6) + (m << 4) + (l4 << 2) + r;
            const float mu = redM[rowb];
            const float rs = redR[rowb];
            #pragma unroll
            for (int n = 0; n < 4; ++n) {
                const int col = (wc << 6) + (n << 4) + l15;
                const float y = (acc[m][n][r] - mu) * rs * g[col] + be[col];
                if (EPI == 1) {
                    outb[(size_t)(bm + rowb) * 256 + col] = f2bf(y);
                } else {
                    float* of = half ? of1 : of0;
                    of[(size_t)(bmL + rowb) * 256 + col] = y;
                }
            }
        }
    }
}

// ---------------- deformable sampling ----------------
// XCD batch-affinity: xcd = wgid&7 processes batch b==xcd (video then audio)
// so each XCD's value working set = 2 x 1.97MB ~ one L2. Desc LDS padded
// (stride 17) so the 8 h-groups hit distinct banks.
struct Desc { float wa, wb; int oa, ob; };

__global__ __launch_bounds__(256) void msda_sample(
    const ushort* __restrict__ value,
    const float* __restrict__ l0, const float* __restrict__ l1,
    const float* __restrict__ a0, const float* __restrict__ a1,
    const int* __restrict__ ts0, const int* __restrict__ lsi0,
    const int* __restrict__ ts1, const int* __restrict__ lsi1,
    ushort* __restrict__ out)
{
    __shared__ Desc ds[544];   // [4 rows][8 h][17 pad]
    const int tid = threadIdx.x;
    const int wg = blockIdx.x;
    const int xcd = wg & 7;
    const int idx = wg >> 3;               // 0..1919
    const int half = idx >= 960;
    const int rowL0 = xcd * SS + (half ? idx - 960 : idx) * 4;
    const int row0 = rowL0 + (half ? RR : 0);

    const float* loc = half ? l1 : l0;
    const float* aw  = half ? a1 : a0;
    const int* ts  = half ? ts1 : ts0;
    const int* lsi = half ? lsi1 : lsi0;
    const ushort* val = value + (size_t)half * NHALF;

    #pragma unroll
    for (int d = tid; d < 512; d += 256) {
        const int rl = d >> 7;
        const int rem = d & 127;           // h*16 + l*4 + p
        const int l = (rem >> 2) & 3;
        const int h = rem >> 4;
        const int lp = rem & 15;
        const int rowL = rowL0 + rl;
        const float lc = loc[(size_t)rowL * 128 + rem];
        const float w  = aw[(size_t)rowL * 128 + rem];
        const int T = ts[l];
        const int s0 = lsi[l];
        const int b = rowL / SS;
        const float pos = lc * (float)T - 0.5f;
        const float x0 = floorf(pos);
        const float w1 = pos - x0;
        const int i0 = (int)x0;
        const int i1 = i0 + 1;
        const int base = (b * 8 + h) * SS + s0;
        Desc e;
        e.wa = (i0 >= 0 && i0 < T) ? w * (1.f - w1) : 0.f;
        e.wb = (i1 >= 0 && i1 < T) ? w * w1 : 0.f;
        const int ia = min(max(i0, 0), T - 1);
        const int ib = min(max(i1, 0), T - 1);
        e.oa = (base + ia) << 5;
        e.ob = (base + ib) << 5;
        ds[(rl * 8 + h) * 17 + lp] = e;
    }
    __syncthreads();

    const int rl = tid >> 6;
    const int h  = (tid >> 3) & 7;
    const int cq = tid & 7;
    const ushort* vb = val + cq * 4;
    const Desc* dd = &ds[(rl * 8 + h) * 17];

    f32x4 acc0 = {}, acc1 = {};
    #pragma unroll
    for (int lp = 0; lp < 16; lp += 2) {
        const Desc e0 = dd[lp];
        const Desc e1 = dd[lp + 1];
        const uint2 A0 = *(const uint2*)(vb + e0.oa);
        const uint2 B0 = *(const uint2*)(vb + e0.ob);
        const uint2 A1 = *(const uint2*)(vb + e1.oa);
        const uint2 B1 = *(const uint2*)(vb + e1.ob);
        #pragma unroll
        for (int c = 0; c < 2; ++c) {
            const uint32_t ua = (c ? A0.y : A0.x), ub = (c ? B0.y : B0.x);
            const uint32_t va = (c ? A1.y : A1.x), vw = (c ? B1.y : B1.x);
            acc0[2*c+0] = fmaf(e0.wa, __builtin_bit_cast(float, ua << 16), acc0[2*c+0]);
            acc0[2*c+1] = fmaf(e0.wa, __builtin_bit_cast(float, ua & 0xFFFF0000u), acc0[2*c+1]);
            acc0[2*c+0] = fmaf(e0.wb, __builtin_bit_cast(float, ub << 16), acc0[2*c+0]);
            acc0[2*c+1] = fmaf(e0.wb, __builtin_bit_cast(float, ub & 0xFFFF0000u), acc0[2*c+1]);
            acc1[2*c+0] = fmaf(e1.wa, __builtin_bit_cast(float, va << 16), acc1[2*c+0]);
            acc1[2*c+1] = fmaf(e1.wa, __builtin_bit_cast(float, va & 0xFFFF0000u), acc1[2*c+1]);
            acc1[2*c+0] = fmaf(e1.wb, __builtin_bit_cast(float, vw << 16), acc1[2*c+0]);
            acc1[2*c+1] = fmaf(e1.wb, __builtin_bit_cast(float, vw & 0xFFFF0000u), acc1[2*c+1]);
        }
    }
    ushort4 o;
    o.x = f2bf(acc0[0] + acc1[0]);
    o.y = f2bf(acc0[1] + acc1[1]);
    o.z = f2bf(acc0[2] + acc1[2]);
    o.w = f2bf(acc0[3] + acc1[3]);
    *(ushort4*)&out[(size_t)(row0 + rl) * 256 + h * 32 + cq * 4] = o;
}

extern "C" void kernel_launch(void* const* d_in, const int* in_sizes, int n_in,
                              void* d_out, int out_size, void* d_ws, size_t ws_size,
                              hipStream_t stream) {
    const float* video_src = (const float*)d_in[0];
    const float* audio_src = (const float*)d_in[1];
    const float* video_pos = (const float*)d_in[2];
    const float* audio_pos = (const float*)d_in[3];
    const float* video_ref = (const float*)d_in[4];
    const float* audio_ref = (const float*)d_in[5];
    const int*   video_ts  = (const int*)d_in[6];
    const int*   video_lsi = (const int*)d_in[7];
    const unsigned char* video_mask = (const unsigned char*)d_in[8];
    const int*   audio_ts  = (const int*)d_in[9];
    const int*   audio_lsi = (const int*)d_in[10];
    const unsigned char* audio_mask = (const unsigned char*)d_in[11];
    const float* Wv = (const float*)d_in[12];
    const float* bv = (const float*)d_in[13];
    const float* Wo = (const float*)d_in[14];
    const float* bo = (const float*)d_in[15];
    const float* Wa = (const float*)d_in[16];
    const float* ba = (const float*)d_in[17];
    const float* Wp = (const float*)d_in[18];
    const float* bp = (const float*)d_in[19];
    const float* ln1_g = (const float*)d_in[20];
    const float* ln1_b = (const float*)d_in[21];
    const float* W1 = (const float*)d_in[22];
    const float* b1 = (const float*)d_in[23];
    const float* W2 = (const float*)d_in[24];
    const float* b2 = (const float*)d_in[25];
    const float* ln2_g = (const float*)d_in[26];
    const float* ln2_b = (const float*)d_in[27];

    float* out = (float*)d_out;
    const size_t n = NHALF;
    float* out_aav  = out;
    float* out_vaa  = out + n;
    float* out_vloc = out + 2 * n;
    float* out_vaw  = out + 2 * n + n / 2;
    float* out_aloc = out + 3 * n;
    float* out_aaw  = out + 3 * n + n / 2;

    const size_t UB = NHALF * 2;   // one bf16 plane, bytes
    char* base = (char*)d_ws;
    ushort* src_cat   = (ushort*)(base + 0 * UB);   // P12
    ushort* q_cat     = (ushort*)(base + 2 * UB);   // P12
    float*  loc_tmp   = (float*) (base + 4 * UB);   // P12
    float*  aw_tmp    = (float*) (base + 6 * UB);   // P12
    ushort* hid       = (ushort*)(base + 0 * UB);   // P34 FFN hidden [0,8U)
    ushort* value_cat = (ushort*)(base + 8 * UB);
    ushort* samp_cat  = (ushort*)(base + 10 * UB);
    ushort* vb_cat    = (ushort*)(base + 12 * UB);
    ushort* proj_b34  = (ushort*)(base + 12 * UB);  // overwrites vb_cat after P34 gemm_fused
    ushort* Wvt  = (ushort*)(base + 14 * UB);
    ushort* Woat = Wvt + 65536;
    ushort* Wpt  = Woat + 65536;
    ushort* W1t  = Wpt + 65536;
    ushort* W2t  = W1t + 262144;
    float*  boa  = (float*)(W2t + 262144);

    wtrans_all<<<2817, 256, 0, stream>>>(Wv, Wo, Wa, Wp, W1, W2, bo, ba,
                                         Wvt, Woat, Wpt, W1t, W2t, boa);
    pack2_cat<<<15360, 256, 0, stream>>>(video_src, audio_src, video_pos, audio_pos,
                                         src_cat, q_cat);

    // ---- Phase 1+2: self-attention ----
    gemm_fused<<<dim3(480, 4), 256, 0, stream>>>(
        src_cat, src_cat + NHALF, q_cat, q_cat + NHALF,
        Wvt, Woat, bv, boa, value_cat,
        loc_tmp, loc_tmp + (size_t)RR * 128, aw_tmp, aw_tmp + (size_t)RR * 128,
        video_ref, audio_ref, video_ts, audio_ts, video_mask, audio_mask);
    msda_sample<<<15360, 256, 0, stream>>>(
        value_cat, loc_tmp, loc_tmp + (size_t)RR * 128, aw_tmp, aw_tmp + (size_t)RR * 128,
        video_ts, video_lsi, audio_ts, audio_lsi, samp_cat);
    gemm256<1><<<dim3(480, 1), 512, 0, stream>>>(
        samp_cat, Wpt, bp, 256, 256, vb_cat,
        video_src, audio_src, nullptr, ln1_g, ln1_b, nullptr, nullptr);

    // ---- Phase 3+4: cross-attention + FFN ----
    gemm_fused<<<dim3(480, 4), 256, 0, stream>>>(
        vb_cat, vb_cat + NHALF,
        vb_cat + NHALF, vb_cat,
        Wvt, Woat, bv, boa, value_cat,
        out_aloc, out_vloc, out_aaw, out_vaw,
        audio_ref, video_ref, video_ts, audio_ts, video_mask, audio_mask);
    msda_sample<<<15360, 256, 0, stream>>>(
        value_cat, out_aloc, out_vloc, out_aaw, out_vaw,
        video_ts, video_lsi, audio_ts, audio_lsi, samp_cat);
    gemm256<0><<<dim3(480, 1), 512, 0, stream>>>(
        samp_cat, Wpt, bp, 256, 256, proj_b34,
        nullptr, nullptr, nullptr, nullptr, nullptr, nullptr, nullptr);
    gemm256<2><<<dim3(480, 4), 512, 0, stream>>>(
        proj_b34, W1t, b1, 1024, 256, hid,
        nullptr, nullptr, nullptr, nullptr, nullptr, nullptr, nullptr);
    gemm256<3><<<dim3(480, 1), 512, 0, stream>>>(
        hid, W2t, b2, 256, 1024, nullptr,
        nullptr, nullptr, proj_b34, ln2_g, ln2_b, out_vaa, out_aav);
}

// Round 9
// 406.640 us; speedup vs baseline: 1.1751x; 1.0740x over previous
//
#include <hip/hip_runtime.h>
#include <hip/hip_bf16.h>
#include <cstdint>

#define BB 8
#define SS 3840
#define RR (BB*SS)                 // 30720 rows per modality
#define NHALF ((size_t)RR * 256)   // elems per half plane

typedef short s16x8 __attribute__((ext_vector_type(8)));
typedef float f32x4 __attribute__((ext_vector_type(4)));
typedef float f32x2 __attribute__((ext_vector_type(2)));

__device__ __forceinline__ ushort f2bf(float f) {
    uint32_t u = __builtin_bit_cast(uint32_t, f);
    u += 0x7FFFu + ((u >> 16) & 1u);
    return (ushort)(u >> 16);
}
__device__ __forceinline__ float bf2f(ushort h) {
    return __builtin_bit_cast(float, (uint32_t)h << 16);
}
// unpack 2 bf16 (one u32) -> f32x2
__device__ __forceinline__ f32x2 up2(uint32_t u) {
    f32x2 r;
    r.x = __builtin_bit_cast(float, u << 16);
    r.y = __builtin_bit_cast(float, u & 0xFFFF0000u);
    return r;
}

#define GLDS16(gp, lp) __builtin_amdgcn_global_load_lds( \
    (const __attribute__((address_space(1))) uint32_t*)(gp), \
    (__attribute__((address_space(3))) uint32_t*)(lp), 16, 0, 0)

// ---------------- all weight prep in one kernel ----------------
__global__ __launch_bounds__(256) void wtrans_all(
    const float* __restrict__ Wv, const float* __restrict__ Wo,
    const float* __restrict__ Wa, const float* __restrict__ Wp,
    const float* __restrict__ W1, const float* __restrict__ W2,
    const float* __restrict__ bo, const float* __restrict__ ba,
    ushort* __restrict__ Wvt, ushort* __restrict__ Woat, ushort* __restrict__ Wpt,
    ushort* __restrict__ W1t, ushort* __restrict__ W2t, float* __restrict__ boa)
{
    int e = blockIdx.x * 256 + threadIdx.x;
    if (e < 65536)       { int k = e >> 8, n = e & 255;  Wvt[n * 256 + k] = f2bf(Wv[e]); }
    else if (e < 98304)  { int i = e - 65536;  int k = i >> 7, n = i & 127;  Woat[n * 256 + k] = f2bf(Wo[i]); }
    else if (e < 131072) { int i = e - 98304;  int k = i >> 7, n = i & 127;  Woat[(n + 128) * 256 + k] = f2bf(Wa[i]); }
    else if (e < 196608) { int i = e - 131072; int k = i >> 8, n = i & 255;  Wpt[n * 256 + k] = f2bf(Wp[i]); }
    else if (e < 458752) { int i = e - 196608; int k = i >> 10, n = i & 1023; W1t[n * 256 + k] = f2bf(W1[i]); }
    else if (e < 720896) { int i = e - 458752; int k = i >> 8, n = i & 255;  W2t[(size_t)n * 1024 + k] = f2bf(W2[i]); }
    else if (e < 721152) { int t = e - 720896; boa[t] = (t < 128) ? bo[t] : ba[t - 128]; }
}

// ---------------- pack both modalities ----------------
__global__ __launch_bounds__(256) void pack2_cat(
    const float* __restrict__ vs, const float* __restrict__ as_,
    const float* __restrict__ vp, const float* __restrict__ ap,
    ushort* __restrict__ sb, ushort* __restrict__ qb)
{
    const int n4 = (int)(NHALF / 4);
    int i = blockIdx.x * 256 + threadIdx.x;
    int j = (i < n4) ? i : i - n4;
    const float4* s4 = (const float4*)((i < n4) ? vs : as_);
    const float4* p4 = (const float4*)((i < n4) ? vp : ap);
    float4 a = s4[j];
    float4 b = p4[j];
    ushort4 u, v;
    u.x = f2bf(a.x); u.y = f2bf(a.y); u.z = f2bf(a.z); u.w = f2bf(a.w);
    v.x = f2bf(a.x + b.x); v.y = f2bf(a.y + b.y); v.z = f2bf(a.z + b.z); v.w = f2bf(a.w + b.w);
    ((ushort4*)sb)[i] = u;
    ((ushort4*)qb)[i] = v;
}

// ---------------- fused value+offaw GEMM, 8-wave 128x256, grid (480, 2) x-major ----------------
// blockIdx.y = job (0 value, 1 offaw). blockIdx.x = bm tile. N=256 per block (A staged once).
__global__ __launch_bounds__(512) void gemm_fused(
    const ushort* __restrict__ Av0, const ushort* __restrict__ Av1,
    const ushort* __restrict__ Ao0, const ushort* __restrict__ Ao1,
    const ushort* __restrict__ WvT, const ushort* __restrict__ WoT,
    const float* __restrict__ bv, const float* __restrict__ boa,
    ushort* __restrict__ val_out,
    float* __restrict__ loc0, float* __restrict__ loc1,
    float* __restrict__ aw0, float* __restrict__ aw1,
    const float* __restrict__ ref0, const float* __restrict__ ref1,
    const int* __restrict__ ts0, const int* __restrict__ ts1,
    const unsigned char* __restrict__ mask0, const unsigned char* __restrict__ mask1)
{
    __shared__ ushort As[128 * 64];
    __shared__ ushort Bs[256 * 64];
    const int tid = threadIdx.x;
    const int lane = tid & 63;
    const int wid = tid >> 6;          // 0..7
    const int wr = wid >> 2, wc = wid & 3;
    const int job = blockIdx.y;
    const int bm = blockIdx.x << 7;
    const int half = bm >= RR;
    const int bmL = half ? bm - RR : bm;
    const int l15 = lane & 15;
    const int l4 = lane >> 4;

    const ushort* A = job ? (half ? Ao1 : Ao0) : (half ? Av1 : Av0);
    const ushort* Wt = job ? WoT : WvT;
    A += (size_t)bmL * 256;

    f32x4 acc[4][4] = {};

    for (int k0 = 0; k0 < 256; k0 += 64) {
        #pragma unroll
        for (int r = 0; r < 2; ++r) {
            int base = r * 512 + (wid << 6);
            int idx = base + lane;
            int row = idx >> 3, sl = idx & 7;
            int ch = sl ^ (row & 7);
            GLDS16(&A[(size_t)row * 256 + k0 + ch * 8], &As[base << 3]);
        }
        #pragma unroll
        for (int r = 0; r < 4; ++r) {
            int base = r * 512 + (wid << 6);
            int idx = base + lane;
            int col = idx >> 3, sl = idx & 7;
            int ch = sl ^ (col & 7);
            GLDS16(&Wt[(size_t)col * 256 + k0 + ch * 8], &Bs[base << 3]);
        }
        __syncthreads();
        #pragma unroll
        for (int ks = 0; ks < 2; ++ks) {
            s16x8 af[4], bf[4];
            const int k16 = ks * 4 + l4;
            #pragma unroll
            for (int m = 0; m < 4; ++m) {
                int row = (wr << 6) + (m << 4) + l15;
                af[m] = *(const s16x8*)&As[(row << 6) + ((k16 ^ (row & 7)) << 3)];
            }
            #pragma unroll
            for (int n = 0; n < 4; ++n) {
                int col = (wc << 6) + (n << 4) + l15;
                bf[n] = *(const s16x8*)&Bs[(col << 6) + ((k16 ^ (col & 7)) << 3)];
            }
            #pragma unroll
            for (int m = 0; m < 4; ++m)
                #pragma unroll
                for (int n = 0; n < 4; ++n)
                    acc[m][n] = __builtin_amdgcn_mfma_f32_16x16x32_bf16(af[m], bf[n], acc[m][n], 0, 0, 0);
        }
        __syncthreads();
    }

    const int l4r = l4 << 2;
    if (job == 0) {
        const unsigned char* mk = half ? mask1 : mask0;
        ushort* vo = val_out + (size_t)half * NHALF;
        #pragma unroll
        for (int m = 0; m < 4; ++m) {
            #pragma unroll
            for (int r = 0; r < 4; ++r) {
                const int rowL = bmL + (wr << 6) + (m << 4) + l4r + r;
                const int b = rowL / SS;
                const int s = rowL - b * SS;
                const float mz = mk[rowL] ? 0.f : 1.f;
                const size_t rb = ((size_t)(b * 8) * SS + s) * 32;
                #pragma unroll
                for (int n = 0; n < 4; ++n) {
                    const int col = (wc << 6) + (n << 4) + l15;
                    const int h = col >> 5, d = col & 31;
                    vo[rb + (size_t)h * (SS * 32) + d] = f2bf((acc[m][n][r] + bv[col]) * mz);
                }
            }
        }
    } else if (wc < 2) {
        // cols [0,128): loc = ref + (off+bo)/ts
        const float* rf = half ? ref1 : ref0;
        const int* tsp = half ? ts1 : ts0;
        const int l = l15 >> 2;
        const float T = (float)tsp[l];
        float* lo = half ? loc1 : loc0;
        #pragma unroll
        for (int m = 0; m < 4; ++m) {
            #pragma unroll
            for (int r = 0; r < 4; ++r) {
                const int rowL = bmL + (wr << 6) + (m << 4) + l4r + r;
                const float refv = rf[(size_t)rowL * 4 + l];
                #pragma unroll
                for (int n = 0; n < 4; ++n) {
                    const int cc = (wc << 6) + (n << 4) + l15;
                    lo[(size_t)rowL * 128 + cc] = refv + (acc[m][n][r] + boa[cc]) / T;
                }
            }
        }
    } else {
        // cols [128,256): softmax over 16 per head
        float* ao = half ? aw1 : aw0;
        #pragma unroll
        for (int m = 0; m < 4; ++m) {
            #pragma unroll
            for (int r = 0; r < 4; ++r) {
                const int rowL = bmL + (wr << 6) + (m << 4) + l4r + r;
                #pragma unroll
                for (int n = 0; n < 4; ++n) {
                    const int cc = (wc << 6) + (n << 4) + l15;   // 128..255
                    float c = acc[m][n][r] + boa[cc];
                    float mx = c;
                    #pragma unroll
                    for (int o = 1; o < 16; o <<= 1) mx = fmaxf(mx, __shfl_xor(mx, o));
                    float e = __expf(c - mx);
                    float sm = e;
                    #pragma unroll
                    for (int o = 1; o < 16; o <<= 1) sm += __shfl_xor(sm, o);
                    ao[(size_t)rowL * 128 + (cc - 128)] = e / sm;
                }
            }
        }
    }
}

// ---------------- 8-wave 128x256 GEMM with fused epilogues ----------------
// EPI 0: + bias -> bf16 (proj P34)
// EPI 1: + bias + f32 residual -> LN -> bf16 (proj+LN1)
// EPI 2: + bias -> relu -> bf16 (FFN W1, N=1024; grid (480,4) x-major)
// EPI 3: + bias + bf16 residual -> LN -> f32 by half (FFN W2+LN2)
template<int EPI>
__global__ __launch_bounds__(512) void gemm256(
    const ushort* __restrict__ A, const ushort* __restrict__ Wt,
    const float* __restrict__ bias, int N, int K,
    ushort* __restrict__ outb,
    const float* __restrict__ res0, const float* __restrict__ res1,
    const ushort* __restrict__ resb,
    const float* __restrict__ g, const float* __restrict__ be,
    float* __restrict__ of0, float* __restrict__ of1)
{
    __shared__ ushort As[128 * 64];
    __shared__ ushort Bs[256 * 64];
    __shared__ float redS[128][4];
    __shared__ float redQ[128][4];
    __shared__ float redM[128];
    __shared__ float redR[128];

    const int tid = threadIdx.x;
    const int lane = tid & 63;
    const int wid = tid >> 6;          // 0..7
    const int wr = wid >> 2, wc = wid & 3;
    const int bm = blockIdx.x << 7;
    const int bn = blockIdx.y << 8;
    const int l15 = lane & 15;
    const int l4 = lane >> 4;

    f32x4 acc[4][4] = {};

    for (int k0 = 0; k0 < K; k0 += 64) {
        #pragma unroll
        for (int r = 0; r < 2; ++r) {
            int base = r * 512 + (wid << 6);
            int idx = base + lane;
            int row = idx >> 3, sl = idx & 7;
            int ch = sl ^ (row & 7);
            GLDS16(&A[(size_t)(bm + row) * K + k0 + ch * 8], &As[base << 3]);
        }
        #pragma unroll
        for (int r = 0; r < 4; ++r) {
            int base = r * 512 + (wid << 6);
            int idx = base + lane;
            int col = idx >> 3, sl = idx & 7;
            int ch = sl ^ (col & 7);
            GLDS16(&Wt[(size_t)(bn + col) * K + k0 + ch * 8], &Bs[base << 3]);
        }
        __syncthreads();
        #pragma unroll
        for (int ks = 0; ks < 2; ++ks) {
            s16x8 af[4], bf[4];
            const int k16 = ks * 4 + l4;
            #pragma unroll
            for (int m = 0; m < 4; ++m) {
                int row = (wr << 6) + (m << 4) + l15;
                af[m] = *(const s16x8*)&As[(row << 6) + ((k16 ^ (row & 7)) << 3)];
            }
            #pragma unroll
            for (int n = 0; n < 4; ++n) {
                int col = (wc << 6) + (n << 4) + l15;
                bf[n] = *(const s16x8*)&Bs[(col << 6) + ((k16 ^ (col & 7)) << 3)];
            }
            #pragma unroll
            for (int m = 0; m < 4; ++m)
                #pragma unroll
                for (int n = 0; n < 4; ++n)
                    acc[m][n] = __builtin_amdgcn_mfma_f32_16x16x32_bf16(af[m], bf[n], acc[m][n], 0, 0, 0);
        }
        __syncthreads();
    }

    const int half = bm >= RR;
    const int bmL = half ? bm - RR : bm;

    if (EPI == 0 || EPI == 2) {
        #pragma unroll
        for (int m = 0; m < 4; ++m) {
            #pragma unroll
            for (int r = 0; r < 4; ++r) {
                const int row = bm + (wr << 6) + (m << 4) + (l4 << 2) + r;
                #pragma unroll
                for (int n = 0; n < 4; ++n) {
                    const int col = bn + (wc << 6) + (n << 4) + l15;
                    float c = acc[m][n][r] + bias[col];
                    if (EPI == 2) c = fmaxf(c, 0.f);
                    outb[(size_t)row * N + col] = f2bf(c);
                }
            }
        }
        return;
    }

    #pragma unroll
    for (int m = 0; m < 4; ++m) {
        #pragma unroll
        for (int r = 0; r < 4; ++r) {
            const int rowb = (wr << 6) + (m << 4) + (l4 << 2) + r;
            float s1 = 0.f, s2 = 0.f;
            #pragma unroll
            for (int n = 0; n < 4; ++n) {
                const int col = (wc << 6) + (n << 4) + l15;
                float x = acc[m][n][r] + bias[col];
                if (EPI == 1) {
                    const float* res = half ? res1 : res0;
                    x += res[(size_t)(bmL + rowb) * 256 + col];
                } else {
                    x += bf2f(resb[(size_t)(bm + rowb) * 256 + col]);
                }
                acc[m][n][r] = x;
                s1 += x;
                s2 += x * x;
            }
            #pragma unroll
            for (int o = 1; o < 16; o <<= 1) {
                s1 += __shfl_xor(s1, o);
                s2 += __shfl_xor(s2, o);
            }
            if (l15 == 0) { redS[rowb][wc] = s1; redQ[rowb][wc] = s2; }
        }
    }
    __syncthreads();
    if (tid < 128) {
        const float S1 = redS[tid][0] + redS[tid][1] + redS[tid][2] + redS[tid][3];
        const float S2 = redQ[tid][0] + redQ[tid][1] + redQ[tid][2] + redQ[tid][3];
        const float mu = S1 * (1.f / 256.f);
        float var = S2 * (1.f / 256.f) - mu * mu;
        var = fmaxf(var, 0.f);
        redM[tid] = mu;
        redR[tid] = rsqrtf(var + 1e-5f);
    }
    __syncthreads();
    #pragma unroll
    for (int m = 0; m < 4; ++m) {
        #pragma unroll
        for (int r = 0; r < 4; ++r) {
            const int rowb = (wr << 6) + (m << 4) + (l4 << 2) + r;
            const float mu = redM[rowb];
            const float rs = redR[rowb];
            #pragma unroll
            for (int n = 0; n < 4; ++n) {
                const int col = (wc << 6) + (n << 4) + l15;
                const float y = (acc[m][n][r] - mu) * rs * g[col] + be[col];
                if (EPI == 1) {
                    outb[(size_t)(bm + rowb) * 256 + col] = f2bf(y);
                } else {
                    float* of = half ? of1 : of0;
                    of[(size_t)(bmL + rowb) * 256 + col] = y;
                }
            }
        }
    }
}

// ---------------- deformable sampling ----------------
// 8 rows/block (grid 7680). XCD batch-affinity (wg&7 -> batch). 4 lanes per
// (row,h), each owning 8 channels: uint4 (16B) gathers, f32x2 packed FMA.
// Desc LDS stride 17 (bank-conflict-free).
struct Desc { float wa, wb; int oa, ob; };

__global__ __launch_bounds__(256) void msda_sample(
    const ushort* __restrict__ value,
    const float* __restrict__ l0, const float* __restrict__ l1,
    const float* __restrict__ a0, const float* __restrict__ a1,
    const int* __restrict__ ts0, const int* __restrict__ lsi0,
    const int* __restrict__ ts1, const int* __restrict__ lsi1,
    ushort* __restrict__ out)
{
    __shared__ Desc ds[64 * 17];   // [8 rows][8 h][17 pad]
    const int tid = threadIdx.x;
    const int wg = blockIdx.x;
    const int xcd = wg & 7;
    const int idx = wg >> 3;               // 0..959
    const int half = idx >= 480;
    const int idxL = half ? idx - 480 : idx;
    const int rowL0 = xcd * SS + idxL * 8;
    const int row0 = rowL0 + (half ? RR : 0);

    const float* loc = half ? l1 : l0;
    const float* aw  = half ? a1 : a0;
    const int* ts  = half ? ts1 : ts0;
    const int* lsi = half ? lsi1 : lsi0;
    const ushort* val = value + (size_t)half * NHALF;

    #pragma unroll
    for (int d = tid; d < 1024; d += 256) {
        const int rl = d >> 7;             // 0..7
        const int rem = d & 127;           // h*16 + l*4 + p
        const int l = (rem >> 2) & 3;
        const int h = rem >> 4;
        const int lp = rem & 15;
        const int rowL = rowL0 + rl;
        const float lc = loc[(size_t)rowL * 128 + rem];
        const float w  = aw[(size_t)rowL * 128 + rem];
        const int T = ts[l];
        const int s0 = lsi[l];
        const int b = rowL / SS;
        const float pos = lc * (float)T - 0.5f;
        const float x0 = floorf(pos);
        const float w1 = pos - x0;
        const int i0 = (int)x0;
        const int i1 = i0 + 1;
        const int base = (b * 8 + h) * SS + s0;
        Desc e;
        e.wa = (i0 >= 0 && i0 < T) ? w * (1.f - w1) : 0.f;
        e.wb = (i1 >= 0 && i1 < T) ? w * w1 : 0.f;
        const int ia = min(max(i0, 0), T - 1);
        const int ib = min(max(i1, 0), T - 1);
        e.oa = (base + ia) << 5;
        e.ob = (base + ib) << 5;
        ds[(rl * 8 + h) * 17 + lp] = e;
    }
    __syncthreads();

    const int rl = tid >> 5;               // 0..7
    const int h  = (tid >> 2) & 7;
    const int cq = tid & 3;                // channel-octet
    const ushort* vb = val + cq * 8;
    const Desc* dd = &ds[(rl * 8 + h) * 17];

    f32x2 ac[4] = {};
    #pragma unroll
    for (int lp = 0; lp < 16; ++lp) {
        const Desc e = dd[lp];
        const uint4 A = *(const uint4*)(vb + e.oa);
        const uint4 B = *(const uint4*)(vb + e.ob);
        const f32x2 wa = {e.wa, e.wa};
        const f32x2 wb = {e.wb, e.wb};
        ac[0] = __builtin_elementwise_fma(wa, up2(A.x), ac[0]);
        ac[1] = __builtin_elementwise_fma(wa, up2(A.y), ac[1]);
        ac[2] = __builtin_elementwise_fma(wa, up2(A.z), ac[2]);
        ac[3] = __builtin_elementwise_fma(wa, up2(A.w), ac[3]);
        ac[0] = __builtin_elementwise_fma(wb, up2(B.x), ac[0]);
        ac[1] = __builtin_elementwise_fma(wb, up2(B.y), ac[1]);
        ac[2] = __builtin_elementwise_fma(wb, up2(B.z), ac[2]);
        ac[3] = __builtin_elementwise_fma(wb, up2(B.w), ac[3]);
    }
    s16x8 o;
    o[0] = (short)f2bf(ac[0].x); o[1] = (short)f2bf(ac[0].y);
    o[2] = (short)f2bf(ac[1].x); o[3] = (short)f2bf(ac[1].y);
    o[4] = (short)f2bf(ac[2].x); o[5] = (short)f2bf(ac[2].y);
    o[6] = (short)f2bf(ac[3].x); o[7] = (short)f2bf(ac[3].y);
    *(s16x8*)&out[(size_t)(row0 + rl) * 256 + h * 32 + cq * 8] = o;
}

extern "C" void kernel_launch(void* const* d_in, const int* in_sizes, int n_in,
                              void* d_out, int out_size, void* d_ws, size_t ws_size,
                              hipStream_t stream) {
    const float* video_src = (const float*)d_in[0];
    const float* audio_src = (const float*)d_in[1];
    const float* video_pos = (const float*)d_in[2];
    const float* audio_pos = (const float*)d_in[3];
    const float* video_ref = (const float*)d_in[4];
    const float* audio_ref = (const float*)d_in[5];
    const int*   video_ts  = (const int*)d_in[6];
    const int*   video_lsi = (const int*)d_in[7];
    const unsigned char* video_mask = (const unsigned char*)d_in[8];
    const int*   audio_ts  = (const int*)d_in[9];
    const int*   audio_lsi = (const int*)d_in[10];
    const unsigned char* audio_mask = (const unsigned char*)d_in[11];
    const float* Wv = (const float*)d_in[12];
    const float* bv = (const float*)d_in[13];
    const float* Wo = (const float*)d_in[14];
    const float* bo = (const float*)d_in[15];
    const float* Wa = (const float*)d_in[16];
    const float* ba = (const float*)d_in[17];
    const float* Wp = (const float*)d_in[18];
    const float* bp = (const float*)d_in[19];
    const float* ln1_g = (const float*)d_in[20];
    const float* ln1_b = (const float*)d_in[21];
    const float* W1 = (const float*)d_in[22];
    const float* b1 = (const float*)d_in[23];
    const float* W2 = (const float*)d_in[24];
    const float* b2 = (const float*)d_in[25];
    const float* ln2_g = (const float*)d_in[26];
    const float* ln2_b = (const float*)d_in[27];

    float* out = (float*)d_out;
    const size_t n = NHALF;
    float* out_aav  = out;
    float* out_vaa  = out + n;
    float* out_vloc = out + 2 * n;
    float* out_vaw  = out + 2 * n + n / 2;
    float* out_aloc = out + 3 * n;
    float* out_aaw  = out + 3 * n + n / 2;

    const size_t UB = NHALF * 2;   // one bf16 plane, bytes
    char* base = (char*)d_ws;
    ushort* src_cat   = (ushort*)(base + 0 * UB);   // P12
    ushort* q_cat     = (ushort*)(base + 2 * UB);   // P12
    float*  loc_tmp   = (float*) (base + 4 * UB);   // P12
    float*  aw_tmp    = (float*) (base + 6 * UB);   // P12
    ushort* hid       = (ushort*)(base + 0 * UB);   // P34 FFN hidden [0,8U)
    ushort* value_cat = (ushort*)(base + 8 * UB);
    ushort* samp_cat  = (ushort*)(base + 10 * UB);
    ushort* vb_cat    = (ushort*)(base + 12 * UB);
    ushort* proj_b34  = (ushort*)(base + 12 * UB);  // overwrites vb_cat after P34 gemm_fused
    ushort* Wvt  = (ushort*)(base + 14 * UB);
    ushort* Woat = Wvt + 65536;
    ushort* Wpt  = Woat + 65536;
    ushort* W1t  = Wpt + 65536;
    ushort* W2t  = W1t + 262144;
    float*  boa  = (float*)(W2t + 262144);

    wtrans_all<<<2817, 256, 0, stream>>>(Wv, Wo, Wa, Wp, W1, W2, bo, ba,
                                         Wvt, Woat, Wpt, W1t, W2t, boa);
    pack2_cat<<<15360, 256, 0, stream>>>(video_src, audio_src, video_pos, audio_pos,
                                         src_cat, q_cat);

    // ---- Phase 1+2: self-attention ----
    gemm_fused<<<dim3(480, 2), 512, 0, stream>>>(
        src_cat, src_cat + NHALF, q_cat, q_cat + NHALF,
        Wvt, Woat, bv, boa, value_cat,
        loc_tmp, loc_tmp + (size_t)RR * 128, aw_tmp, aw_tmp + (size_t)RR * 128,
        video_ref, audio_ref, video_ts, audio_ts, video_mask, audio_mask);
    msda_sample<<<7680, 256, 0, stream>>>(
        value_cat, loc_tmp, loc_tmp + (size_t)RR * 128, aw_tmp, aw_tmp + (size_t)RR * 128,
        video_ts, video_lsi, audio_ts, audio_lsi, samp_cat);
    gemm256<1><<<dim3(480, 1), 512, 0, stream>>>(
        samp_cat, Wpt, bp, 256, 256, vb_cat,
        video_src, audio_src, nullptr, ln1_g, ln1_b, nullptr, nullptr);

    // ---- Phase 3+4: cross-attention + FFN ----
    gemm_fused<<<dim3(480, 2), 512, 0, stream>>>(
        vb_cat, vb_cat + NHALF,
        vb_cat + NHALF, vb_cat,
        Wvt, Woat, bv, boa, value_cat,
        out_aloc, out_vloc, out_aaw, out_vaw,
        audio_ref, video_ref, video_ts, audio_ts, video_mask, audio_mask);
    msda_sample<<<7680, 256, 0, stream>>>(
        value_cat, out_aloc, out_vloc, out_aaw, out_vaw,
        video_ts, video_lsi, audio_ts, audio_lsi, samp_cat);
    gemm256<0><<<dim3(480, 1), 512, 0, stream>>>(
        samp_cat, Wpt, bp, 256, 256, proj_b34,
        nullptr, nullptr, nullptr, nullptr, nullptr, nullptr, nullptr);
    gemm256<2><<<dim3(480, 4), 512, 0, stream>>>(
        proj_b34, W1t, b1, 1024, 256, hid,
        nullptr, nullptr, nullptr, nullptr, nullptr, nullptr, nullptr);
    gemm256<3><<<dim3(480, 1), 512, 0, stream>>>(
        hid, W2t, b2, 256, 1024, nullptr,
        nullptr, nullptr, proj_b34, ln2_g, ln2_b, out_vaa, out_aav);
}